// Round 10
// baseline (42.167 us; speedup 1.0000x reference)
//
#include <hip/hip_runtime.h>
#include <hip/hip_bf16.h>

// NT-Xent loss, fused flash-LSE over sim = z z^T / T, bf16 32x32x16 MFMA.
// z pre-packed into FRAGMENT-MAJOR zf (convert kernel):
//   zf[((tile*8 + ks)*64 + l) * 8 .. +8] =
//       bf16(z[tile*32 + (l&31)][(l>>5)*8 + ks*16 .. +8] * PRESCALE)
// LDS-staged A (8KB col-tiles, global_load_lds, double-buffered), reg B.
// ROUND 10: R5-R9 proved time is invariant to VMEM bytes/instrs/LDS/fences
// -> the binder is the TRANS pipe: ~17 v_exp_f32 per 16 elements (71M exp2),
// ~8-16 cyc/wave-op on the narrow trans unit, invisible to VALUBusy.
// Fix: wave-uniform tile skip. Values ~ N(0, 233 log2); row max ~988; a
// 32x32 tile almost never reaches within 30 log2 of the running max ->
// ~95% of CONSUMEs skip all exp2 (pay 15 fmax + 1 ballot). Dropped mass
// <= 254*1024*2^-30 rel ~ 2.5e-4 -> loss error ~1e-4 (threshold 12.32).
// Diag/partner tiles never skip (pos/mask). Deferred-max keeps skip exact.

#define N_TOT 8192
#define B_HALF 4096
#define DIM 128
#define SPLITS 16
#define COLS_PER_SPLIT 512
#define NT 16                              // col-tiles of 32 per block
#define PRESCALE 4.5398159686f             // sqrt(log2(e)/0.07)
#define LN2F 0.6931471805599453f
#define SKIP_MARGIN 30.0f                  // skip tile if tmax <= m - 30 (log2)

typedef __attribute__((ext_vector_type(8))) short bf16x8;
typedef __attribute__((ext_vector_type(16))) float f32x16;

__device__ __forceinline__ unsigned short f2bf_rne(float f) {
    unsigned int u = __float_as_uint(f);
    u += 0x7FFFu + ((u >> 16) & 1u);
    return (unsigned short)(u >> 16);
}

__device__ __forceinline__ void gload16(const void* g, void* l) {
    __builtin_amdgcn_global_load_lds(
        (const __attribute__((address_space(1))) unsigned int*)g,
        (__attribute__((address_space(3))) unsigned int*)l, 16, 0, 0);
}

// ---- kernel 1: convert f32 z_i,z_j -> pre-scaled bf16 fragment-major zf ----
__global__ void convert_kernel(const float* __restrict__ zi,
                               const float* __restrict__ zj,
                               unsigned short* __restrict__ zf) {
    int t = blockIdx.x * 256 + threadIdx.x;   // slot 0..131071
    int l = t & 63;                           // lane slot
    int ks = (t >> 6) & 7;                    // k-step
    int tile = t >> 9;                        // 32-row tile
    int r = tile * 32 + (l & 31);
    int c = (l >> 5) * 8 + ks * 16;
    long si = (long)r * DIM + c;
    const float* src = (si < (long)B_HALF * DIM) ? (zi + si) : (zj + (si - (long)B_HALF * DIM));
    float4 v0 = *(const float4*)src;
    float4 v1 = *(const float4*)(src + 4);
    bf16x8 o;
    o[0] = (short)f2bf_rne(v0.x * PRESCALE);
    o[1] = (short)f2bf_rne(v0.y * PRESCALE);
    o[2] = (short)f2bf_rne(v0.z * PRESCALE);
    o[3] = (short)f2bf_rne(v0.w * PRESCALE);
    o[4] = (short)f2bf_rne(v1.x * PRESCALE);
    o[5] = (short)f2bf_rne(v1.y * PRESCALE);
    o[6] = (short)f2bf_rne(v1.z * PRESCALE);
    o[7] = (short)f2bf_rne(v1.w * PRESCALE);
    *(bf16x8*)(zf + (size_t)t * 8) = o;
}

// consume one 32x32 result tile (acc) for rows [rbase, rbase+32) at
// stream-col base cb into (mv, sv, pv). Deferred-max LSE with wave-uniform
// skip: exp2 block runs only for diag/partner tiles or tiles whose max is
// within SKIP_MARGIN of the running max (almost never for random data).
#define CONSUME(accv, mv, sv, pv, rbase, cbv)                                  \
    do {                                                                       \
        const int cb_ = (cbv);                                                 \
        const int rb_ = (rbase);                                               \
        const bool check_ = (cb_ == rb_ || cb_ == (rb_ ^ B_HALF));             \
        if (check_) {                                                          \
            const int j_ = rb_ + l5;                                           \
            _Pragma("unroll")                                                  \
            for (int q = 0; q < 16; ++q) {                                     \
                int iq = cb_ + (q & 3) + 8 * (q >> 2) + 4 * hb;                \
                if (iq == j_) accv[q] = -INFINITY;                             \
                else if (iq == (j_ ^ B_HALF)) pv = accv[q];                    \
            }                                                                  \
        }                                                                      \
        float x0 = fmaxf(fmaxf(accv[0], accv[1]), accv[2]);                    \
        float x1 = fmaxf(fmaxf(accv[3], accv[4]), accv[5]);                    \
        float x2 = fmaxf(fmaxf(accv[6], accv[7]), accv[8]);                    \
        float x3 = fmaxf(fmaxf(accv[9], accv[10]), accv[11]);                  \
        float x4 = fmaxf(fmaxf(accv[12], accv[13]), accv[14]);                 \
        float y0 = fmaxf(fmaxf(x0, x1), x2);                                   \
        float y1 = fmaxf(fmaxf(x3, x4), accv[15]);                             \
        float tmax = fmaxf(y0, y1);                                            \
        if (check_ || !__all(tmax <= mv - SKIP_MARGIN)) {                      \
            float mn = fmaxf(tmax, mv);                                        \
            float rr = __builtin_amdgcn_exp2f(mv - mn); /* exp2(0)=1 */        \
            float e0 = __builtin_amdgcn_exp2f(accv[0] - mn);                   \
            float e1 = __builtin_amdgcn_exp2f(accv[1] - mn);                   \
            float e2 = __builtin_amdgcn_exp2f(accv[2] - mn);                   \
            float e3 = __builtin_amdgcn_exp2f(accv[3] - mn);                   \
            float e4 = __builtin_amdgcn_exp2f(accv[4] - mn);                   \
            float e5 = __builtin_amdgcn_exp2f(accv[5] - mn);                   \
            float e6 = __builtin_amdgcn_exp2f(accv[6] - mn);                   \
            float e7 = __builtin_amdgcn_exp2f(accv[7] - mn);                   \
            float e8 = __builtin_amdgcn_exp2f(accv[8] - mn);                   \
            float e9 = __builtin_amdgcn_exp2f(accv[9] - mn);                   \
            float ea = __builtin_amdgcn_exp2f(accv[10] - mn);                  \
            float eb = __builtin_amdgcn_exp2f(accv[11] - mn);                  \
            float ec = __builtin_amdgcn_exp2f(accv[12] - mn);                  \
            float ed = __builtin_amdgcn_exp2f(accv[13] - mn);                  \
            float ee = __builtin_amdgcn_exp2f(accv[14] - mn);                  \
            float ef = __builtin_amdgcn_exp2f(accv[15] - mn);                  \
            float t0 = (e0 + e1) + (e2 + e3);                                  \
            float t1 = (e4 + e5) + (e6 + e7);                                  \
            float t2 = (e8 + e9) + (ea + eb);                                  \
            float t3 = (ec + ed) + (ee + ef);                                  \
            sv = sv * rr + ((t0 + t1) + (t2 + t3));                            \
            mv = mn;                                                           \
        }                                                                      \
    } while (0)

#define ZERO16(accv)                                                           \
    do { _Pragma("unroll") for (int q = 0; q < 16; ++q) accv[q] = 0.f; } while (0)

// wave w stages fragments 2w, 2w+1 of col-tile (tIdx0 + t) into lds[b]
#define STAGE(t, b)                                                            \
    do {                                                                       \
        const unsigned short* s_ =                                             \
            zf + ((size_t)(tIdx0 + (t)) * 8 + 2 * w) * 512 + l * 8;            \
        gload16(s_, &lds[b][(2 * w) * 64]);                                    \
        gload16(s_ + 512, &lds[b][(2 * w + 1) * 64]);                          \
    } while (0)

// ---- kernel 2: main fused GEMM + online LSE (LDS-staged A, reg B) ----
// grid: 32 row-blocks (256 rows) x 16 col-splits (512 cols) = 512 blocks,
// 256 threads (4 waves); wave w owns rows rb*256 + w*64 .. +64.
__global__ __launch_bounds__(256, 2) void ntxent_main(
        const unsigned short* __restrict__ zf,
        float* __restrict__ Wm, float* __restrict__ Ws, float* __restrict__ Wp) {
    __shared__ bf16x8 lds[2][512];  // 2 x 8KB col-tile buffers

    const int bid = blockIdx.x;
    const int rb = bid / SPLITS;
    const int sp = bid % SPLITS;
    const int tid = threadIdx.x;
    const int w = tid >> 6;
    const int l = tid & 63;
    const int l5 = l & 31;
    const int hb = l >> 5;

    const int rowbase = rb * 256 + w * 64;
    const int cb0 = sp * COLS_PER_SPLIT;
    const int tIdx0 = cb0 >> 5;

    // B fragments: two 32-row tile-sets, coalesced 1KB loads from zf
    const unsigned short* bp = zf + (size_t)(rowbase >> 5) * 4096 + l * 8;
    bf16x8 b00 = *(const bf16x8*)(bp + 0 * 512);
    bf16x8 b01 = *(const bf16x8*)(bp + 1 * 512);
    bf16x8 b02 = *(const bf16x8*)(bp + 2 * 512);
    bf16x8 b03 = *(const bf16x8*)(bp + 3 * 512);
    bf16x8 b04 = *(const bf16x8*)(bp + 4 * 512);
    bf16x8 b05 = *(const bf16x8*)(bp + 5 * 512);
    bf16x8 b06 = *(const bf16x8*)(bp + 6 * 512);
    bf16x8 b07 = *(const bf16x8*)(bp + 7 * 512);
    const unsigned short* bq = bp + 4096;
    bf16x8 b10 = *(const bf16x8*)(bq + 0 * 512);
    bf16x8 b11 = *(const bf16x8*)(bq + 1 * 512);
    bf16x8 b12 = *(const bf16x8*)(bq + 2 * 512);
    bf16x8 b13 = *(const bf16x8*)(bq + 3 * 512);
    bf16x8 b14 = *(const bf16x8*)(bq + 4 * 512);
    bf16x8 b15 = *(const bf16x8*)(bq + 5 * 512);
    bf16x8 b16 = *(const bf16x8*)(bq + 6 * 512);
    bf16x8 b17 = *(const bf16x8*)(bq + 7 * 512);

    float m0 = -INFINITY, s0 = 0.f, p0 = -INFINITY;
    float m1 = -INFINITY, s1 = 0.f, p1 = -INFINITY;
    f32x16 accA, accB;

    STAGE(0, 0);   // prologue

#pragma unroll 2
    for (int t = 0; t < NT; ++t) {
        // own stage(t) loads are the newest VMEM -> vmcnt(0) completes them
        asm volatile("s_waitcnt vmcnt(0)" ::: "memory");
        __builtin_amdgcn_s_barrier();   // all waves: stage(t) done; buf[(t+1)&1] free
        __builtin_amdgcn_sched_barrier(0);
        if (t + 1 < NT) STAGE(t + 1, (t + 1) & 1);

        const bf16x8* Lb = lds[t & 1];
        bf16x8 f0 = Lb[0 * 64 + l];
        bf16x8 f1 = Lb[1 * 64 + l];
        bf16x8 f2 = Lb[2 * 64 + l];
        bf16x8 f3 = Lb[3 * 64 + l];
        bf16x8 f4 = Lb[4 * 64 + l];
        bf16x8 f5 = Lb[5 * 64 + l];
        bf16x8 f6 = Lb[6 * 64 + l];
        bf16x8 f7 = Lb[7 * 64 + l];

        ZERO16(accA); ZERO16(accB);
        accA = __builtin_amdgcn_mfma_f32_32x32x16_bf16(f0, b00, accA, 0, 0, 0);
        accB = __builtin_amdgcn_mfma_f32_32x32x16_bf16(f0, b10, accB, 0, 0, 0);
        accA = __builtin_amdgcn_mfma_f32_32x32x16_bf16(f1, b01, accA, 0, 0, 0);
        accB = __builtin_amdgcn_mfma_f32_32x32x16_bf16(f1, b11, accB, 0, 0, 0);
        accA = __builtin_amdgcn_mfma_f32_32x32x16_bf16(f2, b02, accA, 0, 0, 0);
        accB = __builtin_amdgcn_mfma_f32_32x32x16_bf16(f2, b12, accB, 0, 0, 0);
        accA = __builtin_amdgcn_mfma_f32_32x32x16_bf16(f3, b03, accA, 0, 0, 0);
        accB = __builtin_amdgcn_mfma_f32_32x32x16_bf16(f3, b13, accB, 0, 0, 0);
        accA = __builtin_amdgcn_mfma_f32_32x32x16_bf16(f4, b04, accA, 0, 0, 0);
        accB = __builtin_amdgcn_mfma_f32_32x32x16_bf16(f4, b14, accB, 0, 0, 0);
        accA = __builtin_amdgcn_mfma_f32_32x32x16_bf16(f5, b05, accA, 0, 0, 0);
        accB = __builtin_amdgcn_mfma_f32_32x32x16_bf16(f5, b15, accB, 0, 0, 0);
        accA = __builtin_amdgcn_mfma_f32_32x32x16_bf16(f6, b06, accA, 0, 0, 0);
        accB = __builtin_amdgcn_mfma_f32_32x32x16_bf16(f6, b16, accB, 0, 0, 0);
        accA = __builtin_amdgcn_mfma_f32_32x32x16_bf16(f7, b07, accA, 0, 0, 0);
        accB = __builtin_amdgcn_mfma_f32_32x32x16_bf16(f7, b17, accB, 0, 0, 0);

        const int cbv = cb0 + t * 32;
        CONSUME(accA, m0, s0, p0, rowbase, cbv);
        CONSUME(accB, m1, s1, p1, rowbase + 32, cbv);
    }

    // lanes l and l^32 hold the same row over disjoint value subsets: merge
    {
        float m2 = __shfl_xor(m0, 32);
        float s2 = __shfl_xor(s0, 32);
        float q2 = __shfl_xor(p0, 32);
        float M = fmaxf(m0, m2);
        s0 = s0 * __builtin_amdgcn_exp2f(m0 - M) + s2 * __builtin_amdgcn_exp2f(m2 - M);
        p0 = fmaxf(p0, q2);
        if (l < 32) {
            int r = rowbase + l;
            Wm[sp * N_TOT + r] = M;
            Ws[sp * N_TOT + r] = s0;
            Wp[sp * N_TOT + r] = p0;
        }
    }
    {
        float m2 = __shfl_xor(m1, 32);
        float s2 = __shfl_xor(s1, 32);
        float q2 = __shfl_xor(p1, 32);
        float M = fmaxf(m1, m2);
        s1 = s1 * __builtin_amdgcn_exp2f(m1 - M) + s2 * __builtin_amdgcn_exp2f(m2 - M);
        p1 = fmaxf(p1, q2);
        if (l < 32) {
            int r = rowbase + 32 + l;
            Wm[sp * N_TOT + r] = M;
            Ws[sp * N_TOT + r] = s1;
            Wp[sp * N_TOT + r] = p1;
        }
    }
}

// ---- kernel 3: merge splits, compute loss, reduce ----
__global__ void merge_kernel(const float* __restrict__ Wm,
                             const float* __restrict__ Ws,
                             const float* __restrict__ Wp,
                             float* __restrict__ out) {
    int r = blockIdx.x * 256 + threadIdx.x; // 0..8191
    float m = -INFINITY, s = 0.f, p = -INFINITY;
#pragma unroll
    for (int sb = 0; sb < SPLITS; ++sb) {
        float m2 = Wm[sb * N_TOT + r];
        float s2 = Ws[sb * N_TOT + r];
        float p2 = Wp[sb * N_TOT + r];
        float M = fmaxf(m, m2);
        s = s * __builtin_amdgcn_exp2f(m - M) + s2 * __builtin_amdgcn_exp2f(m2 - M);
        m = M;
        p = fmaxf(p, p2);
    }
    // aug row = [pos, neg-row]: add exp(pos) once more
    s += __builtin_amdgcn_exp2f(p - m);
    float loss = ((m + __builtin_amdgcn_logf(s)) - p) * LN2F;

#pragma unroll
    for (int off = 32; off >= 1; off >>= 1)
        loss += __shfl_down(loss, off);
    __shared__ float wsum[4];
    if ((threadIdx.x & 63) == 0) wsum[threadIdx.x >> 6] = loss;
    __syncthreads();
    if (threadIdx.x == 0) {
        float t = wsum[0] + wsum[1] + wsum[2] + wsum[3];
        atomicAdd(out, t * (1.0f / (float)N_TOT));
    }
}

extern "C" void kernel_launch(void* const* d_in, const int* in_sizes, int n_in,
                              void* d_out, int out_size, void* d_ws, size_t ws_size,
                              hipStream_t stream) {
    const float* zi = (const float*)d_in[0];
    const float* zj = (const float*)d_in[1];
    float* out = (float*)d_out;

    unsigned short* zf = (unsigned short*)d_ws;                // 2 MB
    float* Wm = (float*)((char*)d_ws + (size_t)N_TOT * DIM * 2);
    float* Ws = Wm + SPLITS * N_TOT;
    float* Wp = Ws + SPLITS * N_TOT;

    hipMemsetAsync(d_out, 0, sizeof(float), stream);
    convert_kernel<<<(N_TOT * DIM / 8) / 256, 256, 0, stream>>>(zi, zj, zf);
    ntxent_main<<<32 * SPLITS, 256, 0, stream>>>(zf, Wm, Ws, Wp);
    merge_kernel<<<N_TOT / 256, 256, 0, stream>>>(Wm, Ws, Wp, out);
}